// Round 1
// baseline (243.360 us; speedup 1.0000x reference)
//
#include <hip/hip_runtime.h>

#define NT 1024
#define ROW 67615

// Node-axis collapse: cur = broadcast of z over the 128 nodes; all ops are
// node-independent -> p0..p4 dead; net collapses to a per-sample chain of tiny
// dense layers; out[n, j] = tanh(h4[n,0]) for all j.
//
// R9: attack the LDS pipe in the dense chain (the kernel's critical path at
// DVFS-depressed clock). Two changes vs R8:
//  1) Register blocking in level_bn: each thread computes NB samples x OB
//     outputs (L0: 4x4) -> 3x fewer ds_read_b128 issues for the same FMAs.
//  2) W panel split by (o % OB): each sub-panel is read at byte-stride-16
//     across lanes -> <=2 lanes/bank (conflict-free), vs the 8-way conflict
//     of the old interleaved panel (stride-32 -> bank group repeats /4 lanes).
// FP accumulation order, bias handling, BN, L4 and write-out are unchanged
// (bitwise-identical results; absmax stayed 0.0 through R2..R8).

struct Params {
  const float* z;
  const int *sv, *tv, *cv;
  const float *se, *te, *ce;
  const float *fcw[5], *fcb[5];
  const float *w[5],  *wb[5];
  const float *g[4],  *be[4];
  float* out;
};

__device__ __forceinline__ void stage_f4(float* dst, const float* src, int n4, int tid) {
  const float4* s = (const float4*)src;
  for (int j = tid; j < n4; j += NT) *(float4*)(dst + 4 * j) = s[j];
}

// W (row-major OUT x COLS global) -> OB split panels:
// panel p (= o % OB) holds outputs o = oq*OB + p at
//   float4 index p*(COLS/4)*(OUT/OB) + c4*(OUT/OB) + oq
// so an inner-loop read across oq lanes is byte-stride-16 (conflict-free).
template<int OB>
__device__ __forceinline__ void stageW(float* dst, const float* src,
                                       int OUT, int COLS, int tid) {
  int oshift = 31 - __clz(OUT);
  int tasks = OUT * (COLS >> 2);
  int TOQ = OUT / OB;
  int pan = (COLS >> 2) * TOQ;                 // float4s per panel
  for (int j = tid; j < tasks; j += NT) {
    int o = j & (OUT - 1), c4 = j >> oshift;
    int p = o & (OB - 1), oq = o / OB;
    *(float4*)(dst + (p * pan + c4 * TOQ + oq) * 4) =
        *(const float4*)(src + o * COLS + 4 * c4);
  }
}

// Weight-region level bases (floats). Per level:
// fcw[FCIN*16] | fcb[16] | Wpanels[COLS*OUT] | wb[OUT] | g[OUT] | be[OUT]
#define WLB0 0
#define WLB1 9680
#define WLB2 12864
#define WLB3 14464
#define WLB4 15528
#define WL_TOT 16340

// wlv -> W panels; wb at +COLS*OUT, g at +COLS*OUT+OUT, be at +COLS*OUT+2*OUT
template<int INC, int OUT, int NB, int OB>
__device__ __forceinline__ void level_bn(int tid,
    const float* __restrict__ curin, int IS, float* __restrict__ curout,
    const float* __restrict__ contl, const float* __restrict__ wlv,
    float* __restrict__ A, float* __restrict__ Bv)
{
  constexpr int COLS = INC + 16;
  constexpr int OFF_WB = COLS * OUT;
  constexpr int NG  = 32 / NB;                 // sample groups
  constexpr int TOQ = OUT / OB;                // output groups
  constexpr int PAN = (COLS / 4) * TOQ;        // float4s per panel
  constexpr int NTHR = NG * TOQ;
  const float4* Wp = (const float4*)wlv;

  if (tid < NTHR) {
    int ng = tid / TOQ, oq = tid % TOQ;
    int n0 = ng * NB, o0 = oq * OB;
    float s[NB][OB];
#pragma unroll
    for (int i = 0; i < NB; i++)
#pragma unroll
      for (int p = 0; p < OB; p++) s[i][p] = wlv[OFF_WB + o0 + p];
#pragma unroll
    for (int c4 = 0; c4 < INC / 4 + 4; c4++) {
      float4 w[OB];
#pragma unroll
      for (int p = 0; p < OB; p++) w[p] = Wp[p * PAN + c4 * TOQ + oq];
#pragma unroll
      for (int i = 0; i < NB; i++) {
        float4 x;
        if (c4 < INC / 4) x = *(const float4*)(curin + (n0 + i) * IS + 4 * c4);
        else              x = *(const float4*)(contl + (n0 + i) * 20 + 4 * (c4 - INC / 4));
#pragma unroll
        for (int p = 0; p < OB; p++)
          s[i][p] += x.x * w[p].x + x.y * w[p].y + x.z * w[p].z + x.w * w[p].w;
      }
    }
#pragma unroll
    for (int i = 0; i < NB; i++) {
#pragma unroll
      for (int p = 0; p < OB; p++) {
        float v = s[i][p];
        s[i][p] = v >= 0.f ? v : 0.2f * v;
      }
      if constexpr (OB == 4) {
        *(float4*)(curout + (n0 + i) * 68 + o0) =
            make_float4(s[i][0], s[i][1], s[i][2], s[i][3]);
      } else {
        *(float2*)(curout + (n0 + i) * 68 + o0) = make_float2(s[i][0], s[i][1]);
      }
    }
  }
  __syncthreads();

  if (tid < OUT) {                              // BN stats over n (population var)
    int o = tid;
    float su = 0.f, sq = 0.f;
#pragma unroll 8
    for (int n = 0; n < 32; n++) { float v = curout[n * 68 + o]; su += v; sq += v * v; }
    float mean = su * (1.f / 32.f);
    float var  = fmaxf(sq * (1.f / 32.f) - mean * mean, 0.f);
    float inv  = rsqrtf(var + 1e-5f);
    float a = wlv[OFF_WB + OUT + o] * inv;
    A[o]  = a;
    Bv[o] = wlv[OFF_WB + 2 * OUT + o] - mean * a;
  }
  __syncthreads();
  constexpr int OSH = (OUT == 64) ? 6 : (OUT == 32) ? 5 : (OUT == 16) ? 4 : 3;
  for (int i = tid; i < 32 * OUT; i += NT) {    // normalize in place
    int n = i >> OSH, o = i & (OUT - 1);
    curout[n * 68 + o] = A[o] * curout[n * 68 + o] + Bv[o];
  }
  __syncthreads();
}

__global__ __launch_bounds__(NT, 1) void fused_kernel(Params P) {
  extern __shared__ __align__(16) float smem[];
  float* zl   = smem;                 // 4096
  float* cat  = zl + 4096;            // 32*52 = 1664
  float* cont = cat + 1664;           // 5*32*20 = 3200
  float* act0 = cont + 3200;          // 32*68 = 2176
  float* act1 = act0 + 2176;          // 2176
  float* A    = act1 + 2176;          // 64
  float* Bv   = A + 64;               // 64
  float* tsh  = Bv + 64;              // 32
  float* wf   = tsh + 32;             // WL_TOT
  int tid = threadIdx.x;

  // ---- one up-front staging burst (all f32, no conversion)
  stage_f4(zl, P.z, 1024, tid);
  if (tid < 512) {
    int n = tid >> 4, c = tid & 15;
    cat[n * 52 + c]      = P.se[P.sv[n] * 16 + c];
    cat[n * 52 + 16 + c] = P.te[P.tv[n] * 16 + c];
    cat[n * 52 + 32 + c] = P.ce[P.cv[n] * 16 + c];
  }
  // L0: FCIN=16 OUT=64 COLS=144
  stage_f4 (wf + WLB0,        P.fcw[0], 64, tid);
  stage_f4 (wf + WLB0 + 256,  P.fcb[0], 4,  tid);
  stageW<4>(wf + WLB0 + 272,  P.w[0], 64, 144, tid);
  stage_f4 (wf + WLB0 + 272 + 9216, P.wb[0], 16, tid);
  stage_f4 (wf + WLB0 + 272 + 9280, P.g[0],  16, tid);
  stage_f4 (wf + WLB0 + 272 + 9344, P.be[0], 16, tid);
  // L1: FCIN=32 OUT=32 COLS=80
  stage_f4 (wf + WLB1,        P.fcw[1], 128, tid);
  stage_f4 (wf + WLB1 + 512,  P.fcb[1], 4,   tid);
  stageW<2>(wf + WLB1 + 528,  P.w[1], 32, 80, tid);
  stage_f4 (wf + WLB1 + 528 + 2560, P.wb[1], 8, tid);
  stage_f4 (wf + WLB1 + 528 + 2592, P.g[1],  8, tid);
  stage_f4 (wf + WLB1 + 528 + 2624, P.be[1], 8, tid);
  // L2: FCIN=48 OUT=16 COLS=48
  stage_f4 (wf + WLB2,        P.fcw[2], 192, tid);
  stage_f4 (wf + WLB2 + 768,  P.fcb[2], 4,   tid);
  stageW<2>(wf + WLB2 + 784,  P.w[2], 16, 48, tid);
  stage_f4 (wf + WLB2 + 784 + 768, P.wb[2], 4, tid);
  stage_f4 (wf + WLB2 + 784 + 784, P.g[2],  4, tid);
  stage_f4 (wf + WLB2 + 784 + 800, P.be[2], 4, tid);
  // L3: FCIN=48 OUT=8 COLS=32
  stage_f4 (wf + WLB3,        P.fcw[3], 192, tid);
  stage_f4 (wf + WLB3 + 768,  P.fcb[3], 4,   tid);
  stageW<2>(wf + WLB3 + 784,  P.w[3], 8, 32, tid);
  stage_f4 (wf + WLB3 + 784 + 256, P.wb[3], 2, tid);
  stage_f4 (wf + WLB3 + 784 + 264, P.g[3],  2, tid);
  stage_f4 (wf + WLB3 + 784 + 272, P.be[3], 2, tid);
  // L4: FCIN=48 OUT=1 COLS=24 (W contiguous)
  stage_f4 (wf + WLB4,        P.fcw[4], 192, tid);
  stage_f4 (wf + WLB4 + 768,  P.fcb[4], 4,   tid);
  stage_f4 (wf + WLB4 + 784,  P.w[4],   6,   tid);
  if (tid == 0) wf[WLB4 + 808] = P.wb[4][0];
  __syncthreads();

  // ---- all 5 contents GEMMs in one pass (depend only on cat)
  if (tid < 640) {
    int lvl = tid >> 7, r = tid & 127, n = r >> 2, cg = r & 3;
    int fcin = (lvl >= 2) ? 48 : (16 << lvl);
    int wb = (lvl == 0) ? WLB0 : (lvl == 1) ? WLB1 : (lvl == 2) ? WLB2
           : (lvl == 3) ? WLB3 : WLB4;
    const float* fw = wf + wb;
    const float* fcb = fw + fcin * 16;
    float a0 = fcb[4 * cg], a1 = fcb[4 * cg + 1], a2 = fcb[4 * cg + 2], a3 = fcb[4 * cg + 3];
    const float4* catp = (const float4*)(cat + n * 52);
    int nk4 = fcin >> 2;
#pragma unroll 4
    for (int k4 = 0; k4 < nk4; k4++) {
      float4 cv = catp[k4];
      float xs[4] = {cv.x, cv.y, cv.z, cv.w};
#pragma unroll
      for (int j = 0; j < 4; j++) {
        float4 w = *(const float4*)(fw + (4 * k4 + j) * 16 + 4 * cg);
        a0 += xs[j] * w.x; a1 += xs[j] * w.y; a2 += xs[j] * w.z; a3 += xs[j] * w.w;
      }
    }
    *(float4*)(cont + lvl * 640 + n * 20 + 4 * cg) = make_float4(a0, a1, a2, a3);
  }
  __syncthreads();

  // ---- dense chain (pure LDS, f32), register-blocked NBxOB tiles
  level_bn<128, 64, 4, 4>(tid, zl,   128, act0, cont,        wf + WLB0 + 272, A, Bv);
  level_bn< 64, 32, 4, 2>(tid, act0,  68, act1, cont + 640,  wf + WLB1 + 528, A, Bv);
  level_bn< 32, 16, 2, 2>(tid, act1,  68, act0, cont + 1280, wf + WLB2 + 784, A, Bv);
  level_bn< 16,  8, 2, 2>(tid, act0,  68, act1, cont + 1920, wf + WLB3 + 784, A, Bv);
  if (tid < 32) {
    const float* w4 = wf + WLB4 + 784;
    float s = wf[WLB4 + 808];
#pragma unroll
    for (int c = 0; c < 8; c++) s += act1[tid * 68 + c] * w4[c];
#pragma unroll
    for (int k = 0; k < 16; k++) s += cont[2560 + tid * 20 + k] * w4[8 + k];
    tsh[tid] = tanhf(s);
  }
  __syncthreads();

  // ---- write this block's slice: row = blockIdx.y, col chunk = blockIdx.x
  int row = blockIdx.y;
  float tv = tsh[row];
  const int CHUNK = 8452;                       // ceil(67615/8)
  int c0 = blockIdx.x * CHUNK;
  int c1 = c0 + CHUNK; if (c1 > ROW) c1 = ROW;

  float* rowp = P.out + (size_t)row * ROW;
  unsigned long long addr = (unsigned long long)(rowp + c0);
  int s = (int)((16u - ((unsigned int)addr & 15u)) & 15u) >> 2;
  int vstart = c0 + s;
  float4 v4 = make_float4(tv, tv, tv, tv);
  for (int e = vstart + tid * 4; e + 4 <= c1; e += NT * 4) *(float4*)(rowp + e) = v4;
  if (tid == 0) {
    int hend = vstart < c1 ? vstart : c1;
    for (int i = c0; i < hend; i++) rowp[i] = tv;
    if (c1 > vstart) {
      int ts = vstart + (((c1 - vstart) >> 2) << 2);
      for (int i = ts; i < c1; i++) rowp[i] = tv;
    }
  }
}

extern "C" void kernel_launch(void* const* d_in, const int* in_sizes, int n_in,
                              void* d_out, int out_size, void* d_ws, size_t ws_size,
                              hipStream_t stream) {
  Params P;
  P.z  = (const float*)d_in[0];
  P.sv = (const int*)d_in[1];
  P.tv = (const int*)d_in[2];
  P.cv = (const int*)d_in[3];
  P.se = (const float*)d_in[4];
  P.te = (const float*)d_in[5];
  P.ce = (const float*)d_in[6];
  for (int i = 0; i < 5; i++) {
    P.fcw[i] = (const float*)d_in[7 + 2 * i];
    P.fcb[i] = (const float*)d_in[8 + 2 * i];
  }
  for (int i = 0; i < 5; i++) {
    P.w[i]  = (const float*)d_in[17 + 2 * i];
    P.wb[i] = (const float*)d_in[18 + 2 * i];
  }
  for (int i = 0; i < 4; i++) {
    P.g[i]  = (const float*)d_in[27 + 2 * i];
    P.be[i] = (const float*)d_in[28 + 2 * i];
  }
  P.out = (float*)d_out;
  // p0..p4 (d_in[35..39]) provably dead; d_ws unused.

  // dynamic LDS: 13472 + 16340 floats = 29812 f = 119248 B (<160 KB, 1 blk/CU)
  size_t smem = (13472 + WL_TOT) * sizeof(float);
  hipLaunchKernelGGL(fused_kernel, dim3(8, 32), dim3(NT), smem, stream, P);
}

// Round 2
// 156.446 us; speedup vs baseline: 1.5556x; 1.5556x over previous
//
#include <hip/hip_runtime.h>

#define NT 1024
#define ROW 67615

// Node-axis collapse: cur = broadcast of z over the 128 nodes; all ops are
// node-independent -> p0..p4 dead; net collapses to a per-sample chain of tiny
// dense layers; out[n, j] = tanh(h4[n,0]) for all j.
//
// R10: revert R9's 4x4 register tiles (they spilled: 200 MB scratch traffic,
// VALUBusy 3.4%, 117 us). Keep the conflict-free W-panel idea but at 1x4
// tiles: ~30 live VGPRs, 512 threads (8 waves) carry L0. W panels split by
// (o % OB) -> a wave's W read is <=16 distinct float4s over 256 contiguous
// bytes = <=2 lanes/bank = conflict-free (R8's interleave was 8-way). zl
// padded to stride 132 so L0 X reads hit distinct bank groups.
// FP accumulation order, bias handling, BN, L4 and write-out unchanged
// (bitwise-identical results; absmax 0.0 through R2..R9).

struct Params {
  const float* z;
  const int *sv, *tv, *cv;
  const float *se, *te, *ce;
  const float *fcw[5], *fcb[5];
  const float *w[5],  *wb[5];
  const float *g[4],  *be[4];
  float* out;
};

__device__ __forceinline__ void stage_f4(float* dst, const float* src, int n4, int tid) {
  const float4* s = (const float4*)src;
  for (int j = tid; j < n4; j += NT) *(float4*)(dst + 4 * j) = s[j];
}

// W (row-major OUT x COLS global) -> OB split panels:
// panel p (= o % OB) holds outputs o = oq*OB + p at
//   float4 index p*(COLS/4)*(OUT/OB) + c4*(OUT/OB) + oq
// so an inner-loop read across oq lanes is byte-stride-16 (conflict-free).
template<int OB>
__device__ __forceinline__ void stageW(float* dst, const float* src,
                                       int OUT, int COLS, int tid) {
  int oshift = 31 - __clz(OUT);
  int tasks = OUT * (COLS >> 2);
  int TOQ = OUT / OB;
  int pan = (COLS >> 2) * TOQ;                 // float4s per panel
  for (int j = tid; j < tasks; j += NT) {
    int o = j & (OUT - 1), c4 = j >> oshift;
    int p = o & (OB - 1), oq = o / OB;
    *(float4*)(dst + (p * pan + c4 * TOQ + oq) * 4) =
        *(const float4*)(src + o * COLS + 4 * c4);
  }
}

// Weight-region level bases (floats). Per level:
// fcw[FCIN*16] | fcb[16] | Wpanels[COLS*OUT] | wb[OUT] | g[OUT] | be[OUT]
#define WLB0 0
#define WLB1 9680
#define WLB2 12864
#define WLB3 14464
#define WLB4 15528
#define WL_TOT 16340

// wlv -> W panels; wb at +COLS*OUT, g at +COLS*OUT+OUT, be at +COLS*OUT+2*OUT
// 1 x OB tile per thread: NTHR = 32 * (OUT/OB) threads active in the GEMM.
template<int INC, int OUT, int OB>
__device__ __forceinline__ void level_bn(int tid,
    const float* __restrict__ curin, int IS, float* __restrict__ curout,
    const float* __restrict__ contl, const float* __restrict__ wlv,
    float* __restrict__ A, float* __restrict__ Bv)
{
  constexpr int COLS = INC + 16;
  constexpr int OFF_WB = COLS * OUT;
  constexpr int TOQ = OUT / OB;                // output groups
  constexpr int PAN = (COLS / 4) * TOQ;        // float4s per panel
  constexpr int NTHR = 32 * TOQ;
  const float4* Wp = (const float4*)wlv;

  if (tid < NTHR) {
    int n = tid / TOQ, oq = tid % TOQ;
    int o0 = oq * OB;
    float s[OB];
#pragma unroll
    for (int p = 0; p < OB; p++) s[p] = wlv[OFF_WB + o0 + p];
#pragma unroll
    for (int c4 = 0; c4 < INC / 4 + 4; c4++) {
      float4 w[OB];
#pragma unroll
      for (int p = 0; p < OB; p++) w[p] = Wp[p * PAN + c4 * TOQ + oq];
      float4 x;
      if (c4 < INC / 4) x = *(const float4*)(curin + n * IS + 4 * c4);
      else              x = *(const float4*)(contl + n * 20 + 4 * (c4 - INC / 4));
#pragma unroll
      for (int p = 0; p < OB; p++)
        s[p] += x.x * w[p].x + x.y * w[p].y + x.z * w[p].z + x.w * w[p].w;
    }
#pragma unroll
    for (int p = 0; p < OB; p++) {
      float v = s[p];
      s[p] = v >= 0.f ? v : 0.2f * v;
    }
    if constexpr (OB == 4) {
      *(float4*)(curout + n * 68 + o0) = make_float4(s[0], s[1], s[2], s[3]);
    } else {
      *(float2*)(curout + n * 68 + o0) = make_float2(s[0], s[1]);
    }
  }
  __syncthreads();

  if (tid < OUT) {                              // BN stats over n (population var)
    int o = tid;
    float su = 0.f, sq = 0.f;
#pragma unroll 8
    for (int n = 0; n < 32; n++) { float v = curout[n * 68 + o]; su += v; sq += v * v; }
    float mean = su * (1.f / 32.f);
    float var  = fmaxf(sq * (1.f / 32.f) - mean * mean, 0.f);
    float inv  = rsqrtf(var + 1e-5f);
    float a = wlv[OFF_WB + OUT + o] * inv;
    A[o]  = a;
    Bv[o] = wlv[OFF_WB + 2 * OUT + o] - mean * a;
  }
  __syncthreads();
  constexpr int OSH = (OUT == 64) ? 6 : (OUT == 32) ? 5 : (OUT == 16) ? 4 : 3;
  for (int i = tid; i < 32 * OUT; i += NT) {    // normalize in place
    int n = i >> OSH, o = i & (OUT - 1);
    curout[n * 68 + o] = A[o] * curout[n * 68 + o] + Bv[o];
  }
  __syncthreads();
}

__global__ __launch_bounds__(NT, 1) void fused_kernel(Params P) {
  extern __shared__ __align__(16) float smem[];
  float* zl   = smem;                 // 32*132 = 4224 (stride 132: bank-spread)
  float* cat  = zl + 4224;            // 32*52 = 1664
  float* cont = cat + 1664;           // 5*32*20 = 3200
  float* act0 = cont + 3200;          // 32*68 = 2176
  float* act1 = act0 + 2176;          // 2176
  float* A    = act1 + 2176;          // 64
  float* Bv   = A + 64;               // 64
  float* tsh  = Bv + 64;              // 32
  float* wf   = tsh + 32;             // WL_TOT
  int tid = threadIdx.x;

  // ---- one up-front staging burst (all f32, no conversion)
  {
    const float4* s = (const float4*)P.z;       // z is (32,128) contiguous
    for (int j = tid; j < 1024; j += NT) {
      int n = j >> 5, c4 = j & 31;
      *(float4*)(zl + n * 132 + 4 * c4) = s[j];
    }
  }
  if (tid < 512) {
    int n = tid >> 4, c = tid & 15;
    cat[n * 52 + c]      = P.se[P.sv[n] * 16 + c];
    cat[n * 52 + 16 + c] = P.te[P.tv[n] * 16 + c];
    cat[n * 52 + 32 + c] = P.ce[P.cv[n] * 16 + c];
  }
  // L0: FCIN=16 OUT=64 COLS=144
  stage_f4 (wf + WLB0,        P.fcw[0], 64, tid);
  stage_f4 (wf + WLB0 + 256,  P.fcb[0], 4,  tid);
  stageW<4>(wf + WLB0 + 272,  P.w[0], 64, 144, tid);
  stage_f4 (wf + WLB0 + 272 + 9216, P.wb[0], 16, tid);
  stage_f4 (wf + WLB0 + 272 + 9280, P.g[0],  16, tid);
  stage_f4 (wf + WLB0 + 272 + 9344, P.be[0], 16, tid);
  // L1: FCIN=32 OUT=32 COLS=80
  stage_f4 (wf + WLB1,        P.fcw[1], 128, tid);
  stage_f4 (wf + WLB1 + 512,  P.fcb[1], 4,   tid);
  stageW<4>(wf + WLB1 + 528,  P.w[1], 32, 80, tid);
  stage_f4 (wf + WLB1 + 528 + 2560, P.wb[1], 8, tid);
  stage_f4 (wf + WLB1 + 528 + 2592, P.g[1],  8, tid);
  stage_f4 (wf + WLB1 + 528 + 2624, P.be[1], 8, tid);
  // L2: FCIN=48 OUT=16 COLS=48
  stage_f4 (wf + WLB2,        P.fcw[2], 192, tid);
  stage_f4 (wf + WLB2 + 768,  P.fcb[2], 4,   tid);
  stageW<4>(wf + WLB2 + 784,  P.w[2], 16, 48, tid);
  stage_f4 (wf + WLB2 + 784 + 768, P.wb[2], 4, tid);
  stage_f4 (wf + WLB2 + 784 + 784, P.g[2],  4, tid);
  stage_f4 (wf + WLB2 + 784 + 800, P.be[2], 4, tid);
  // L3: FCIN=48 OUT=8 COLS=32
  stage_f4 (wf + WLB3,        P.fcw[3], 192, tid);
  stage_f4 (wf + WLB3 + 768,  P.fcb[3], 4,   tid);
  stageW<2>(wf + WLB3 + 784,  P.w[3], 8, 32, tid);
  stage_f4 (wf + WLB3 + 784 + 256, P.wb[3], 2, tid);
  stage_f4 (wf + WLB3 + 784 + 264, P.g[3],  2, tid);
  stage_f4 (wf + WLB3 + 784 + 272, P.be[3], 2, tid);
  // L4: FCIN=48 OUT=1 COLS=24 (W contiguous)
  stage_f4 (wf + WLB4,        P.fcw[4], 192, tid);
  stage_f4 (wf + WLB4 + 768,  P.fcb[4], 4,   tid);
  stage_f4 (wf + WLB4 + 784,  P.w[4],   6,   tid);
  if (tid == 0) wf[WLB4 + 808] = P.wb[4][0];
  __syncthreads();

  // ---- all 5 contents GEMMs in one pass (depend only on cat)
  if (tid < 640) {
    int lvl = tid >> 7, r = tid & 127, n = r >> 2, cg = r & 3;
    int fcin = (lvl >= 2) ? 48 : (16 << lvl);
    int wb = (lvl == 0) ? WLB0 : (lvl == 1) ? WLB1 : (lvl == 2) ? WLB2
           : (lvl == 3) ? WLB3 : WLB4;
    const float* fw = wf + wb;
    const float* fcb = fw + fcin * 16;
    float a0 = fcb[4 * cg], a1 = fcb[4 * cg + 1], a2 = fcb[4 * cg + 2], a3 = fcb[4 * cg + 3];
    const float4* catp = (const float4*)(cat + n * 52);
    int nk4 = fcin >> 2;
#pragma unroll 4
    for (int k4 = 0; k4 < nk4; k4++) {
      float4 cv = catp[k4];
      float xs[4] = {cv.x, cv.y, cv.z, cv.w};
#pragma unroll
      for (int j = 0; j < 4; j++) {
        float4 w = *(const float4*)(fw + (4 * k4 + j) * 16 + 4 * cg);
        a0 += xs[j] * w.x; a1 += xs[j] * w.y; a2 += xs[j] * w.z; a3 += xs[j] * w.w;
      }
    }
    *(float4*)(cont + lvl * 640 + n * 20 + 4 * cg) = make_float4(a0, a1, a2, a3);
  }
  __syncthreads();

  // ---- dense chain (pure LDS, f32), 1xOB register tiles
  level_bn<128, 64, 4>(tid, zl,  132, act0, cont,        wf + WLB0 + 272, A, Bv);
  level_bn< 64, 32, 4>(tid, act0, 68, act1, cont + 640,  wf + WLB1 + 528, A, Bv);
  level_bn< 32, 16, 4>(tid, act1, 68, act0, cont + 1280, wf + WLB2 + 784, A, Bv);
  level_bn< 16,  8, 2>(tid, act0, 68, act1, cont + 1920, wf + WLB3 + 784, A, Bv);
  if (tid < 32) {
    const float* w4 = wf + WLB4 + 784;
    float s = wf[WLB4 + 808];
#pragma unroll
    for (int c = 0; c < 8; c++) s += act1[tid * 68 + c] * w4[c];
#pragma unroll
    for (int k = 0; k < 16; k++) s += cont[2560 + tid * 20 + k] * w4[8 + k];
    tsh[tid] = tanhf(s);
  }
  __syncthreads();

  // ---- write this block's slice: row = blockIdx.y, col chunk = blockIdx.x
  int row = blockIdx.y;
  float tv = tsh[row];
  const int CHUNK = 8452;                       // ceil(67615/8)
  int c0 = blockIdx.x * CHUNK;
  int c1 = c0 + CHUNK; if (c1 > ROW) c1 = ROW;

  float* rowp = P.out + (size_t)row * ROW;
  unsigned long long addr = (unsigned long long)(rowp + c0);
  int s = (int)((16u - ((unsigned int)addr & 15u)) & 15u) >> 2;
  int vstart = c0 + s;
  float4 v4 = make_float4(tv, tv, tv, tv);
  for (int e = vstart + tid * 4; e + 4 <= c1; e += NT * 4) *(float4*)(rowp + e) = v4;
  if (tid == 0) {
    int hend = vstart < c1 ? vstart : c1;
    for (int i = c0; i < hend; i++) rowp[i] = tv;
    if (c1 > vstart) {
      int ts = vstart + (((c1 - vstart) >> 2) << 2);
      for (int i = ts; i < c1; i++) rowp[i] = tv;
    }
  }
}

extern "C" void kernel_launch(void* const* d_in, const int* in_sizes, int n_in,
                              void* d_out, int out_size, void* d_ws, size_t ws_size,
                              hipStream_t stream) {
  Params P;
  P.z  = (const float*)d_in[0];
  P.sv = (const int*)d_in[1];
  P.tv = (const int*)d_in[2];
  P.cv = (const int*)d_in[3];
  P.se = (const float*)d_in[4];
  P.te = (const float*)d_in[5];
  P.ce = (const float*)d_in[6];
  for (int i = 0; i < 5; i++) {
    P.fcw[i] = (const float*)d_in[7 + 2 * i];
    P.fcb[i] = (const float*)d_in[8 + 2 * i];
  }
  for (int i = 0; i < 5; i++) {
    P.w[i]  = (const float*)d_in[17 + 2 * i];
    P.wb[i] = (const float*)d_in[18 + 2 * i];
  }
  for (int i = 0; i < 4; i++) {
    P.g[i]  = (const float*)d_in[27 + 2 * i];
    P.be[i] = (const float*)d_in[28 + 2 * i];
  }
  P.out = (float*)d_out;
  // p0..p4 (d_in[35..39]) provably dead; d_ws unused.

  // dynamic LDS: 13600 + 16340 floats = 29940 f = 119760 B (<160 KB, 1 blk/CU)
  size_t smem = (13600 + WL_TOT) * sizeof(float);
  hipLaunchKernelGGL(fused_kernel, dim3(8, 32), dim3(NT), smem, stream, P);
}